// Round 1
// baseline (1153.625 us; speedup 1.0000x reference)
//
#include <hip/hip_runtime.h>

#define Bn 64
#define Nn 1024
#define Cc 128

// ---------------- layer-1 featurize: x0 = nf @ W_in, ai/aj scores ----------------
__global__ __launch_bounds__(128) void k_featurize(
    const float* __restrict__ nf, const float* __restrict__ Win,
    const float* __restrict__ asrc, const float* __restrict__ adst,
    float* __restrict__ x0, float* __restrict__ ai, float* __restrict__ aj) {
  int row = blockIdx.x;          // b*N + n
  int c = threadIdx.x;           // 0..127
  float f0 = nf[row*3+0], f1 = nf[row*3+1], f2 = nf[row*3+2];
  float x = f0*Win[c] + f1*Win[Cc+c] + f2*Win[2*Cc+c];
  x0[(size_t)row*Cc + c] = x;
  float s = x*asrc[c], d = x*adst[c];
  #pragma unroll
  for (int off=32; off>0; off>>=1){ s += __shfl_down(s,off,64); d += __shfl_down(d,off,64); }
  __shared__ float ls[2], ld[2];
  int wave=c>>6, lane=c&63;
  if (lane==0){ ls[wave]=s; ld[wave]=d; }
  __syncthreads();
  if (c==0){ ai[row]=ls[0]+ls[1]; aj[row]=ld[0]+ld[1]; }
}

// ---------------- layer-2 scores ----------------
__global__ __launch_bounds__(128) void k_scores(
    const float* __restrict__ x,
    const float* __restrict__ asrc, const float* __restrict__ adst,
    float* __restrict__ ai, float* __restrict__ aj) {
  int row = blockIdx.x;
  int c = threadIdx.x;
  float xv = x[(size_t)row*Cc + c];
  float s = xv*asrc[c], d = xv*adst[c];
  #pragma unroll
  for (int off=32; off>0; off>>=1){ s += __shfl_down(s,off,64); d += __shfl_down(d,off,64); }
  __shared__ float ls[2], ld[2];
  int wave=c>>6, lane=c&63;
  if (lane==0){ ls[wave]=s; ld[wave]=d; }
  __syncthreads();
  if (c==0){ ai[row]=ls[0]+ls[1]; aj[row]=ld[0]+ld[1]; }
}

// ------- layer-1 row stats: softmax denominator + bit-pack adjacency mask -------
__global__ __launch_bounds__(256) void k_rowstats_pack(
    const int* __restrict__ adj, const float* __restrict__ ai, const float* __restrict__ aj,
    float* __restrict__ denom, unsigned long long* __restrict__ pm) {
  int row = blockIdx.x;            // b*N + i
  int b = row >> 10;
  const int* arow = adj + (size_t)row * Nn;
  const float* ajb = aj + ((size_t)b << 10);
  float av = ai[row];
  int t = threadIdx.x;
  float sum = 0.f;
  #pragma unroll
  for (int k=0;k<4;k++){
    int j = t + (k<<8);
    int m = arow[j];
    unsigned long long bal = __ballot(m>0);
    if ((t&63)==0) pm[(size_t)row*16 + (j>>6)] = bal;  // wave's 64 lanes = contiguous j span
    float e = av + ajb[j];
    e = e>0.f ? e : 0.2f*e;
    sum += (m>0) ? __expf(e) : 0.f;
  }
  #pragma unroll
  for (int off=32;off>0;off>>=1) sum += __shfl_down(sum,off,64);
  __shared__ float ls[4];
  if ((t&63)==0) ls[t>>6]=sum;
  __syncthreads();
  if (t==0) denom[row]=ls[0]+ls[1]+ls[2]+ls[3];
}

// ------- layer-2 row stats: reads packed mask (8.4 MB instead of 268 MB) -------
__global__ __launch_bounds__(256) void k_rowstats_pm(
    const unsigned long long* __restrict__ pm, const float* __restrict__ ai,
    const float* __restrict__ aj, float* __restrict__ denom) {
  int row = blockIdx.x;
  int b = row >> 10;
  const float* ajb = aj + ((size_t)b << 10);
  float av = ai[row];
  int t = threadIdx.x;
  float sum = 0.f;
  #pragma unroll
  for (int k=0;k<4;k++){
    int j = t + (k<<8);
    unsigned long long w = pm[(size_t)row*16 + (j>>6)];
    bool m = (w >> (j&63)) & 1ULL;
    float e = av + ajb[j];
    e = e>0.f ? e : 0.2f*e;
    sum += m ? __expf(e) : 0.f;
  }
  #pragma unroll
  for (int off=32;off>0;off>>=1) sum += __shfl_down(sum,off,64);
  __shared__ float ls[4];
  if ((t&63)==0) ls[t>>6]=sum;
  __syncthreads();
  if (t==0) denom[row]=ls[0]+ls[1]+ls[2]+ls[3];
}

// ------- aggregation: out[i,c] = relu( (1/den[i]) * sum_j w_ij * x[j,c] ) -------
// block: 64 i-rows x 128 c; thread: 4i x 8c register tile; K-tile = 32 j
__global__ __launch_bounds__(256) void k_aggregate(
    const float* __restrict__ xin, const float* __restrict__ ai, const float* __restrict__ aj,
    const float* __restrict__ denom, const unsigned long long* __restrict__ pm,
    float* __restrict__ xout) {
  const int b  = blockIdx.y;
  const int i0 = blockIdx.x << 6;      // 64 rows per block
  const int tid = threadIdx.x;
  __shared__ float Wt[32][64];         // [jj][ii]
  __shared__ float Xt[32][Cc];
  __shared__ float ai_s[64], rd_s[64];
  const int baserow = (b<<10) + i0;
  if (tid < 64) { ai_s[tid] = ai[baserow+tid]; rd_s[tid] = 1.0f / denom[baserow+tid]; }
  const float* xb  = xin + (((size_t)b)<<10)*Cc;
  const float* ajb = aj  + (((size_t)b)<<10);
  const int ti = tid>>4;               // 0..15 -> rows i0 + ti*4 .. +3
  const int tc = tid&15;               // cols tc*8 .. +7
  const int wjj  = tid>>3;             // weight row (j within tile) this thread cooks
  const int wii0 = (tid&7)<<3;         // 8 consecutive ii
  float acc[4][8] = {};
  for (int jt=0; jt<Nn; jt+=32) {
    __syncthreads();                   // prev FMA done; ai_s visible on first iter
    // stage X tile: 32x128 floats, 4 float4 per thread
    #pragma unroll
    for (int k=0;k<4;k++){
      int f = tid + (k<<8);
      int r = f>>5, c4 = f&31;
      ((float4*)&Xt[0][0])[f] = ((const float4*)(xb + (size_t)(jt+r)*Cc))[c4];
    }
    // cook weights: w = mask ? exp(lrelu(ai+aj)) : 0
    float ajv = ajb[jt + wjj];
    int shift = (jt&63) + wjj;
    size_t wix = (size_t)(jt>>6);
    float wloc[8];
    #pragma unroll
    for (int k=0;k<8;k++){
      int ii = wii0 + k;
      unsigned long long pw = pm[(size_t)(baserow+ii)*16 + wix];
      float e = ai_s[ii] + ajv;
      e = e>0.f ? e : 0.2f*e;
      wloc[k] = ((pw>>shift)&1ULL) ? __expf(e) : 0.f;
    }
    *(float4*)&Wt[wjj][wii0]   = make_float4(wloc[0],wloc[1],wloc[2],wloc[3]);
    *(float4*)&Wt[wjj][wii0+4] = make_float4(wloc[4],wloc[5],wloc[6],wloc[7]);
    __syncthreads();
    // FMA loop
    #pragma unroll 8
    for (int kk=0;kk<32;kk++){
      float4 wf  = *(const float4*)&Wt[kk][ti<<2];
      float4 xa  = *(const float4*)&Xt[kk][tc<<3];
      float4 xb4 = *(const float4*)&Xt[kk][(tc<<3)+4];
      float wv[4] = {wf.x,wf.y,wf.z,wf.w};
      float xv[8] = {xa.x,xa.y,xa.z,xa.w,xb4.x,xb4.y,xb4.z,xb4.w};
      #pragma unroll
      for (int r=0;r<4;r++)
        #pragma unroll
        for (int cc2=0;cc2<8;cc2++) acc[r][cc2] += wv[r]*xv[cc2];
    }
  }
  // epilogue: scale by 1/denom, relu, store
  #pragma unroll
  for (int r=0;r<4;r++){
    int i = i0 + (ti<<2) + r;
    float rdv = rd_s[(ti<<2)+r];
    float o[8];
    #pragma unroll
    for (int cc2=0;cc2<8;cc2++) o[cc2] = fmaxf(acc[r][cc2]*rdv, 0.f);
    float4* dst = (float4*)(xout + (size_t)((b<<10)+i)*Cc + (tc<<3));
    dst[0] = make_float4(o[0],o[1],o[2],o[3]);
    dst[1] = make_float4(o[4],o[5],o[6],o[7]);
  }
}

// ---------------- mean over N (partial sums + atomics; xm pre-zeroed) ----------------
__global__ __launch_bounds__(128) void k_mean(const float* __restrict__ x, float* __restrict__ xm){
  int b = blockIdx.x, ch = blockIdx.y, c = threadIdx.x;
  const float* p = x + (((size_t)b<<10) + ((size_t)ch<<7))*Cc + c;
  float s=0.f;
  #pragma unroll 8
  for (int n=0;n<128;n++) s += p[(size_t)n*Cc];
  atomicAdd(&xm[(b<<7)+c], s);
}

// ---------------- fused MLP head: h1 -> h2 -> (softmax pi, v) ----------------
__global__ __launch_bounds__(256) void k_head(
    const float* __restrict__ xm, const float* __restrict__ W1, const float* __restrict__ b1,
    const float* __restrict__ W2, const float* __restrict__ b2,
    const float* __restrict__ Wpi, const float* __restrict__ bpi,
    const float* __restrict__ Wv, const float* __restrict__ bv,
    float* __restrict__ out) {
  int b = blockIdx.x, t = threadIdx.x;
  __shared__ float xs[128], h1[256], h2[128], red[4];
  if (t<128) xs[t] = xm[(b<<7)+t] * (1.f/1024.f);
  __syncthreads();
  float s = 0.f;
  #pragma unroll 8
  for (int k=0;k<128;k++) s += xs[k]*W1[k*256+t];
  h1[t] = fmaxf(s + b1[t], 0.f);
  __syncthreads();
  if (t<128){
    float s2=0.f;
    #pragma unroll 8
    for (int k=0;k<256;k++) s2 += h1[k]*W2[k*128+t];
    h2[t] = fmaxf(s2 + b2[t], 0.f);
  }
  __syncthreads();
  float lg[4];
  #pragma unroll
  for (int q=0;q<4;q++){
    int o = t + (q<<8);
    float s3=0.f;
    #pragma unroll 8
    for (int k=0;k<128;k++) s3 += h2[k]*Wpi[k*1024+o];
    lg[q] = s3 + bpi[o];
  }
  // block max
  float mx = fmaxf(fmaxf(lg[0],lg[1]),fmaxf(lg[2],lg[3]));
  #pragma unroll
  for (int off=32;off>0;off>>=1) mx = fmaxf(mx, __shfl_down(mx,off,64));
  if ((t&63)==0) red[t>>6]=mx;
  __syncthreads();
  mx = fmaxf(fmaxf(red[0],red[1]),fmaxf(red[2],red[3]));
  __syncthreads();
  float ex[4]; float sum=0.f;
  #pragma unroll
  for (int q=0;q<4;q++){ ex[q]=__expf(lg[q]-mx); sum+=ex[q]; }
  #pragma unroll
  for (int off=32;off>0;off>>=1) sum += __shfl_down(sum,off,64);
  if ((t&63)==0) red[t>>6]=sum;
  __syncthreads();
  sum = red[0]+red[1]+red[2]+red[3];
  float rs = 1.0f/sum;
  #pragma unroll
  for (int q=0;q<4;q++) out[((size_t)b<<10) + t + (q<<8)] = ex[q]*rs;
  __syncthreads();
  float vp = (t<128) ? h2[t]*Wv[t] : 0.f;
  #pragma unroll
  for (int off=32;off>0;off>>=1) vp += __shfl_down(vp,off,64);
  if ((t&63)==0) red[t>>6]=vp;
  __syncthreads();
  if (t==0) out[65536 + b] = red[0]+red[1]+red[2]+red[3] + bv[0];
}

extern "C" void kernel_launch(void* const* d_in, const int* in_sizes, int n_in,
                              void* d_out, int out_size, void* d_ws, size_t ws_size,
                              hipStream_t stream) {
  const float* nf    = (const float*)d_in[0];
  const int*   adj   = (const int*)  d_in[1];
  const float* Win   = (const float*)d_in[2];
  const float* asrc  = (const float*)d_in[3];
  const float* adst  = (const float*)d_in[4];
  const float* asrc2 = (const float*)d_in[5];
  const float* adst2 = (const float*)d_in[6];
  const float* W1    = (const float*)d_in[7];
  const float* b1    = (const float*)d_in[8];
  const float* W2    = (const float*)d_in[9];
  const float* b2    = (const float*)d_in[10];
  const float* Wpi   = (const float*)d_in[11];
  const float* bpi   = (const float*)d_in[12];
  const float* Wv    = (const float*)d_in[13];
  const float* bv    = (const float*)d_in[14];
  float* out = (float*)d_out;

  char* ws = (char*)d_ws;
  float* x0 = (float*)(ws);                                  // 33.55 MB
  float* x1 = (float*)(ws + 33554432);                       // 33.55 MB
  unsigned long long* pm = (unsigned long long*)(ws + 67108864); // 8.39 MB packed mask
  float* ai1 = (float*)(ws + 75497472);
  float* aj1 = (float*)(ws + 75759616);
  float* den1= (float*)(ws + 76021760);
  float* ai2 = (float*)(ws + 76283904);
  float* aj2 = (float*)(ws + 76546048);
  float* den2= (float*)(ws + 76808192);
  float* xm  = (float*)(ws + 77070336);                      // 32 KB

  k_featurize<<<Bn*Nn, 128, 0, stream>>>(nf, Win, asrc, adst, x0, ai1, aj1);
  k_rowstats_pack<<<Bn*Nn, 256, 0, stream>>>(adj, ai1, aj1, den1, pm);
  dim3 ag(Nn/64, Bn);
  k_aggregate<<<ag, 256, 0, stream>>>(x0, ai1, aj1, den1, pm, x1);
  k_scores<<<Bn*Nn, 128, 0, stream>>>(x1, asrc2, adst2, ai2, aj2);
  k_rowstats_pm<<<Bn*Nn, 256, 0, stream>>>(pm, ai2, aj2, den2);
  k_aggregate<<<ag, 256, 0, stream>>>(x1, ai2, aj2, den2, pm, x0);
  hipMemsetAsync(xm, 0, Bn*Cc*sizeof(float), stream);
  dim3 gm(Bn, 8);
  k_mean<<<gm, 128, 0, stream>>>(x0, xm);
  k_head<<<Bn, 256, 0, stream>>>(xm, W1, b1, W2, b2, Wpi, bpi, Wv, bv, out);
}

// Round 3
// 713.634 us; speedup vs baseline: 1.6165x; 1.6165x over previous
//
#include <hip/hip_runtime.h>

#define Bn 64
#define Nn 1024
#define Cc 128

typedef _Float16 h8 __attribute__((ext_vector_type(8)));
typedef float f4v __attribute__((ext_vector_type(4)));

// ---------------- featurize: x0 = nf @ W_in (fp16 grouped layout), ai/aj + exp tables ----------------
// grouped layout per batch: element (n,c) at ((n>>3)*128 + c)*8 + (n&7)
__global__ __launch_bounds__(256) void k_feat(
    const float* __restrict__ nf, const float* __restrict__ Win,
    const float* __restrict__ asrc, const float* __restrict__ adst,
    _Float16* __restrict__ X0, float* __restrict__ ai, float* __restrict__ aj,
    float* __restrict__ E, float* __restrict__ G, float* __restrict__ F, float* __restrict__ H) {
  int g = blockIdx.x; int b = g >> 7; int n0 = (g & 127) << 3;
  int t = threadIdx.x; int c = t >> 1; int h = t & 1;
  float w0 = Win[c], w1 = Win[Cc + c], w2 = Win[2 * Cc + c];
  float as_ = asrc[c], ad = adst[c];
  float ps[4], pd[4];
  _Float16 hv[4];
  #pragma unroll
  for (int r = 0; r < 4; r++) {
    int n = n0 + (h << 2) + r;
    const float* p = nf + ((size_t)(b << 10) + n) * 3;
    float x = p[0] * w0 + p[1] * w1 + p[2] * w2;
    hv[r] = (_Float16)x; ps[r] = x * as_; pd[r] = x * ad;
  }
  *(uint2*)(X0 + ((size_t)b << 17) + ((size_t)(g & 127) << 10) + (c << 3) + (h << 2)) = *(uint2*)hv;
  #pragma unroll
  for (int off = 32; off > 1; off >>= 1) {
    #pragma unroll
    for (int r = 0; r < 4; r++) { ps[r] += __shfl_down(ps[r], off, 64); pd[r] += __shfl_down(pd[r], off, 64); }
  }
  __shared__ float red[4][2][4][2];
  int lane = t & 63, wv = t >> 6;
  if (lane < 2) {
    #pragma unroll
    for (int r = 0; r < 4; r++) { red[wv][lane][r][0] = ps[r]; red[wv][lane][r][1] = pd[r]; }
  }
  __syncthreads();
  if (t < 8) {
    int hh = t >> 2, r = t & 3;
    float sa = 0.f, sd = 0.f;
    #pragma unroll
    for (int w = 0; w < 4; w++) { sa += red[w][hh][r][0]; sd += red[w][hh][r][1]; }
    int gi = (b << 10) + n0 + t;
    ai[gi] = sa; aj[gi] = sd;
    E[gi] = __expf(sa); G[gi] = __expf(0.2f * sa);
    F[gi] = __expf(sd); H[gi] = __expf(0.2f * sd);
  }
}

// ---------------- layer-2 scores from fp16 grouped x1 ----------------
__global__ __launch_bounds__(256) void k_scores2(
    const _Float16* __restrict__ X1,
    const float* __restrict__ asrc, const float* __restrict__ adst,
    float* __restrict__ ai, float* __restrict__ aj,
    float* __restrict__ E, float* __restrict__ G, float* __restrict__ F, float* __restrict__ H) {
  int g = blockIdx.x; int b = g >> 7; int n0 = (g & 127) << 3;
  int t = threadIdx.x; int c = t >> 1; int h = t & 1;
  float as_ = asrc[c], ad = adst[c];
  uint2 raw = *(const uint2*)(X1 + ((size_t)b << 17) + ((size_t)(g & 127) << 10) + (c << 3) + (h << 2));
  const _Float16* hp = (const _Float16*)&raw;
  float ps[4], pd[4];
  #pragma unroll
  for (int r = 0; r < 4; r++) { float x = (float)hp[r]; ps[r] = x * as_; pd[r] = x * ad; }
  #pragma unroll
  for (int off = 32; off > 1; off >>= 1) {
    #pragma unroll
    for (int r = 0; r < 4; r++) { ps[r] += __shfl_down(ps[r], off, 64); pd[r] += __shfl_down(pd[r], off, 64); }
  }
  __shared__ float red[4][2][4][2];
  int lane = t & 63, wv = t >> 6;
  if (lane < 2) {
    #pragma unroll
    for (int r = 0; r < 4; r++) { red[wv][lane][r][0] = ps[r]; red[wv][lane][r][1] = pd[r]; }
  }
  __syncthreads();
  if (t < 8) {
    int hh = t >> 2, r = t & 3;
    float sa = 0.f, sd = 0.f;
    #pragma unroll
    for (int w = 0; w < 4; w++) { sa += red[w][hh][r][0]; sd += red[w][hh][r][1]; }
    int gi = (b << 10) + n0 + t;
    ai[gi] = sa; aj[gi] = sd;
    E[gi] = __expf(sa); G[gi] = __expf(0.2f * sa);
    F[gi] = __expf(sd); H[gi] = __expf(0.2f * sd);
  }
}

// ------- layer-1 row stats: softmax denominator + bit-pack adjacency mask -------
__global__ __launch_bounds__(256) void k_rowstats_pack(
    const int* __restrict__ adj, const float* __restrict__ ai, const float* __restrict__ aj,
    float* __restrict__ denom, unsigned long long* __restrict__ pm) {
  int row = blockIdx.x;
  int b = row >> 10;
  const int* arow = adj + (size_t)row * Nn;
  const float* ajb = aj + ((size_t)b << 10);
  float av = ai[row];
  int t = threadIdx.x;
  float sum = 0.f;
  #pragma unroll
  for (int k = 0; k < 4; k++) {
    int j = t + (k << 8);
    int m = arow[j];
    unsigned long long bal = __ballot(m > 0);
    if ((t & 63) == 0) pm[(size_t)row * 16 + (j >> 6)] = bal;
    float e = av + ajb[j];
    e = e > 0.f ? e : 0.2f * e;
    sum += (m > 0) ? __expf(e) : 0.f;
  }
  #pragma unroll
  for (int off = 32; off > 0; off >>= 1) sum += __shfl_down(sum, off, 64);
  __shared__ float ls[4];
  if ((t & 63) == 0) ls[t >> 6] = sum;
  __syncthreads();
  if (t == 0) denom[row] = ls[0] + ls[1] + ls[2] + ls[3];
}

// ------- layer-2 row stats from packed mask -------
__global__ __launch_bounds__(256) void k_rowstats_pm(
    const unsigned long long* __restrict__ pm, const float* __restrict__ ai,
    const float* __restrict__ aj, float* __restrict__ denom) {
  int row = blockIdx.x;
  int b = row >> 10;
  const float* ajb = aj + ((size_t)b << 10);
  float av = ai[row];
  int t = threadIdx.x;
  float sum = 0.f;
  #pragma unroll
  for (int k = 0; k < 4; k++) {
    int j = t + (k << 8);
    unsigned long long w = pm[(size_t)row * 16 + (j >> 6)];
    bool m = (w >> (j & 63)) & 1ULL;
    float e = av + ajb[j];
    e = e > 0.f ? e : 0.2f * e;
    sum += m ? __expf(e) : 0.f;
  }
  #pragma unroll
  for (int off = 32; off > 0; off >>= 1) sum += __shfl_down(sum, off, 64);
  __shared__ float ls[4];
  if ((t & 63) == 0) ls[t >> 6] = sum;
  __syncthreads();
  if (t == 0) denom[row] = ls[0] + ls[1] + ls[2] + ls[3];
}

// ------- MFMA aggregation: out[i,c] = relu( sum_j alpha_ij * x[j,c] ), alpha includes 1/den -------
// block: 64 i x 128 c, 4 waves (wave tile 32i x 64c), K-step 32 j, fp16 16x16x32 MFMA
// B-tile staged via VGPRs (no async LDS); deterministic epilogue (no atomics).
template <int LAYER>
__global__ __launch_bounds__(256, 4) void k_agg(
    const _Float16* __restrict__ X,
    const float* __restrict__ ai, const float* __restrict__ E, const float* __restrict__ G,
    const float* __restrict__ aj, const float* __restrict__ F, const float* __restrict__ H,
    const float* __restrict__ den, const unsigned long long* __restrict__ pm,
    _Float16* __restrict__ Y, float* __restrict__ xmp) {
  __shared__ __align__(16) char smem[34048];
  _Float16* sB = (_Float16*)smem;                       // 8192 B: x tile, grouped copy
  _Float16* sA = (_Float16*)(smem + 8192);              // 4096 B: alpha tile [jg][i][8]
  float* s_aj = (float*)(smem + 12288);                 // 4 KB each
  float* s_F  = (float*)(smem + 16384);
  float* s_H  = (float*)(smem + 20480);
  unsigned char* s_pm = (unsigned char*)(smem + 24576); // 64 rows x 148 B (padded)
  float* tile = (float*)smem;                           // epilogue overlay [64][132]

  const int b = blockIdx.y, i0 = blockIdx.x << 6;
  const int tid = threadIdx.x;
  const int lane = tid & 63, wv = tid >> 6;
  const int m = lane & 15, quad = lane >> 4;
  const int wi = wv >> 1, wc = wv & 1;
  const int gbase = b << 10;

  // stage col-side arrays (aj, F, H) for all 1024 j
  {
    ((float4*)s_aj)[tid] = ((const float4*)(aj + gbase))[tid];
    ((float4*)s_F)[tid]  = ((const float4*)(F + gbase))[tid];
    ((float4*)s_H)[tid]  = ((const float4*)(H + gbase))[tid];
  }
  // stage packed mask rows into padded LDS
  {
    const unsigned int* psrc = (const unsigned int*)(pm + (size_t)(gbase + i0) * 16);
    #pragma unroll
    for (int k = tid; k < 2048; k += 256) {
      int r = k >> 5, cc = k & 31;
      *(unsigned int*)&s_pm[r * 148 + (cc << 2)] = psrc[k];
    }
  }
  // per-thread A-gen row constants (thread owns row i = lane, j-group = wv)
  const int gi = gbase + i0 + lane;
  const float ai_i = ai[gi];
  const float rdv = 1.0f / den[gi];
  const float Ed = E[gi] * rdv, Gd = G[gi] * rdv;

  f4v acc[2][4];
  #pragma unroll
  for (int a = 0; a < 2; a++)
    #pragma unroll
    for (int ct = 0; ct < 4; ct++) { f4v z = {0.f, 0.f, 0.f, 0.f}; acc[a][ct] = z; }

  const char* xb = (const char*)(X + ((size_t)b << 17));
  __syncthreads();  // static staging (s_aj/s_F/s_H/s_pm) visible to all waves

  for (int kt = 0; kt < 32; ++kt) {
    const int jt = kt << 5;
    // B-tile slice -> VGPRs (grouped layout is contiguous per tile)
    const char* gsrc = xb + (jt << 8) + (wv << 11) + lane * 16;
    uint4 r0 = *(const uint4*)gsrc;
    uint4 r1 = *(const uint4*)(gsrc + 1024);
    // A-gen: alpha for (i = lane, j = jt + wv*8 + jj)
    h8 af;
    {
      const int j0 = jt + (wv << 3);
      float aw[8], fw[8], hw[8];
      *(float4*)&aw[0] = *(const float4*)&s_aj[j0]; *(float4*)&aw[4] = *(const float4*)&s_aj[j0 + 4];
      *(float4*)&fw[0] = *(const float4*)&s_F[j0];  *(float4*)&fw[4] = *(const float4*)&s_F[j0 + 4];
      *(float4*)&hw[0] = *(const float4*)&s_H[j0];  *(float4*)&hw[4] = *(const float4*)&s_H[j0 + 4];
      unsigned int mbyte = s_pm[lane * 148 + (jt >> 3) + wv];
      #pragma unroll
      for (int jj = 0; jj < 8; jj++) {
        float e = ai_i + aw[jj];
        bool pos = e > 0.f;
        float wi_ = pos ? Ed : Gd;
        float wj_ = pos ? fw[jj] : hw[jj];
        float val = ((mbyte >> jj) & 1u) ? wi_ * wj_ : 0.f;
        af[jj] = (_Float16)val;
      }
    }
    __syncthreads();  // prev-iter MFMA ds_reads of sA/sB complete
    {
      char* ldst = (char*)sB + (wv << 11) + lane * 16;
      *(uint4*)ldst = r0;
      *(uint4*)(ldst + 1024) = r1;
      *((h8*)sA + (wv << 6) + lane) = af;
    }
    __syncthreads();  // sB + sA visible
    // MFMA
    {
      const h8* pA = (const h8*)sA;
      const h8* pB = (const h8*)sB;
      h8 a0 = pA[(quad << 6) + (wi << 5) + m];
      h8 a1 = pA[(quad << 6) + (wi << 5) + 16 + m];
      #pragma unroll
      for (int ct = 0; ct < 4; ct++) {
        h8 bf = pB[(quad << 7) + (wc << 6) + (ct << 4) + m];
        acc[0][ct] = __builtin_amdgcn_mfma_f32_16x16x32_f16(a0, bf, acc[0][ct], 0, 0, 0);
        acc[1][ct] = __builtin_amdgcn_mfma_f32_16x16x32_f16(a1, bf, acc[1][ct], 0, 0, 0);
      }
    }
  }
  __syncthreads();  // K-loop LDS reads done before overlay
  // write relu(acc) into fp32 tile [64][132]
  #pragma unroll
  for (int a = 0; a < 2; a++)
    #pragma unroll
    for (int ct = 0; ct < 4; ct++)
      #pragma unroll
      for (int r = 0; r < 4; r++) {
        int lr = (wi << 5) + (a << 4) + (quad << 2) + r;
        int c = (wc << 6) + (ct << 4) + m;
        tile[lr * 132 + c] = fmaxf(acc[a][ct][r], 0.f);
      }
  __syncthreads();
  if (LAYER == 1) {
    // coalesced fp16 grouped-layout store: block region is contiguous [i0*128, +8192)
    _Float16 hv[32];
    #pragma unroll
    for (int s = 0; s < 32; s++) {
      int q = (tid << 5) + s;
      int li = ((q >> 10) << 3) + (q & 7), c = (q >> 3) & 127;
      hv[s] = (_Float16)tile[li * 132 + c];
    }
    uint4* o = (uint4*)(Y + ((size_t)b << 17) + ((size_t)i0 << 7) + (tid << 5));
    o[0] = *(uint4*)&hv[0]; o[1] = *(uint4*)&hv[8];
    o[2] = *(uint4*)&hv[16]; o[3] = *(uint4*)&hv[24];
  } else {
    // node-mean partial: column sums -> per-(block,batch) partial slot (deterministic)
    if (tid < 128) {
      float s = 0.f;
      #pragma unroll
      for (int i = 0; i < 64; i++) s += tile[i * 132 + tid];
      xmp[(((b << 4) + blockIdx.x) << 7) + tid] = s;
    }
  }
}

// ---------------- fused MLP head (sums the 16 mean-partials) ----------------
__global__ __launch_bounds__(256) void k_head(
    const float* __restrict__ xmp, const float* __restrict__ W1, const float* __restrict__ b1,
    const float* __restrict__ W2, const float* __restrict__ b2,
    const float* __restrict__ Wpi, const float* __restrict__ bpi,
    const float* __restrict__ Wv, const float* __restrict__ bv,
    float* __restrict__ out) {
  int b = blockIdx.x, t = threadIdx.x;
  __shared__ float xs[128], h1[256], h2[128], red[4];
  if (t < 128) {
    const float* p = xmp + ((size_t)b << 11);
    float s = 0.f;
    #pragma unroll
    for (int xb = 0; xb < 16; xb++) s += p[(xb << 7) + t];
    xs[t] = s * (1.f / 1024.f);
  }
  __syncthreads();
  float s = 0.f;
  #pragma unroll 8
  for (int k = 0; k < 128; k++) s += xs[k] * W1[k * 256 + t];
  h1[t] = fmaxf(s + b1[t], 0.f);
  __syncthreads();
  if (t < 128) {
    float s2 = 0.f;
    #pragma unroll 8
    for (int k = 0; k < 256; k++) s2 += h1[k] * W2[k * 128 + t];
    h2[t] = fmaxf(s2 + b2[t], 0.f);
  }
  __syncthreads();
  float lg[4];
  #pragma unroll
  for (int q = 0; q < 4; q++) {
    int o = t + (q << 8);
    float s3 = 0.f;
    #pragma unroll 8
    for (int k = 0; k < 128; k++) s3 += h2[k] * Wpi[k * 1024 + o];
    lg[q] = s3 + bpi[o];
  }
  float mx = fmaxf(fmaxf(lg[0], lg[1]), fmaxf(lg[2], lg[3]));
  #pragma unroll
  for (int off = 32; off > 0; off >>= 1) mx = fmaxf(mx, __shfl_down(mx, off, 64));
  if ((t & 63) == 0) red[t >> 6] = mx;
  __syncthreads();
  mx = fmaxf(fmaxf(red[0], red[1]), fmaxf(red[2], red[3]));
  __syncthreads();
  float ex[4]; float sum = 0.f;
  #pragma unroll
  for (int q = 0; q < 4; q++) { ex[q] = __expf(lg[q] - mx); sum += ex[q]; }
  #pragma unroll
  for (int off = 32; off > 0; off >>= 1) sum += __shfl_down(sum, off, 64);
  if ((t & 63) == 0) red[t >> 6] = sum;
  __syncthreads();
  sum = red[0] + red[1] + red[2] + red[3];
  float rs = 1.0f / sum;
  #pragma unroll
  for (int q = 0; q < 4; q++) out[((size_t)b << 10) + t + (q << 8)] = ex[q] * rs;
  __syncthreads();
  float vp = (t < 128) ? h2[t] * Wv[t] : 0.f;
  #pragma unroll
  for (int off = 32; off > 0; off >>= 1) vp += __shfl_down(vp, off, 64);
  if ((t & 63) == 0) red[t >> 6] = vp;
  __syncthreads();
  if (t == 0) out[65536 + b] = red[0] + red[1] + red[2] + red[3] + bv[0];
}

extern "C" void kernel_launch(void* const* d_in, const int* in_sizes, int n_in,
                              void* d_out, int out_size, void* d_ws, size_t ws_size,
                              hipStream_t stream) {
  const float* nf    = (const float*)d_in[0];
  const int*   adj   = (const int*)  d_in[1];
  const float* Win   = (const float*)d_in[2];
  const float* asrc  = (const float*)d_in[3];
  const float* adst  = (const float*)d_in[4];
  const float* asrc2 = (const float*)d_in[5];
  const float* adst2 = (const float*)d_in[6];
  const float* W1    = (const float*)d_in[7];
  const float* b1    = (const float*)d_in[8];
  const float* W2    = (const float*)d_in[9];
  const float* b2    = (const float*)d_in[10];
  const float* Wpi   = (const float*)d_in[11];
  const float* bpi   = (const float*)d_in[12];
  const float* Wv    = (const float*)d_in[13];
  const float* bv    = (const float*)d_in[14];
  float* out = (float*)d_out;

  char* ws = (char*)d_ws;
  _Float16* x0 = (_Float16*)(ws);                                // 16.78 MB
  _Float16* x1 = (_Float16*)(ws + 16777216);                     // 16.78 MB
  unsigned long long* pm = (unsigned long long*)(ws + 33554432); // 8.39 MB
  char* S = ws + 41943040;
  float* ai1 = (float*)(S + 0 * 262144);
  float* aj1 = (float*)(S + 1 * 262144);
  float* E1  = (float*)(S + 2 * 262144);
  float* G1  = (float*)(S + 3 * 262144);
  float* F1  = (float*)(S + 4 * 262144);
  float* H1  = (float*)(S + 5 * 262144);
  float* den1= (float*)(S + 6 * 262144);
  float* ai2 = (float*)(S + 7 * 262144);
  float* aj2 = (float*)(S + 8 * 262144);
  float* E2  = (float*)(S + 9 * 262144);
  float* G2  = (float*)(S + 10 * 262144);
  float* F2  = (float*)(S + 11 * 262144);
  float* H2  = (float*)(S + 12 * 262144);
  float* den2= (float*)(S + 13 * 262144);
  float* xmp = (float*)(S + 14 * 262144);                        // 512 KB partials

  k_feat<<<8192, 256, 0, stream>>>(nf, Win, asrc, adst, x0, ai1, aj1, E1, G1, F1, H1);
  k_rowstats_pack<<<Bn * Nn, 256, 0, stream>>>(adj, ai1, aj1, den1, pm);
  dim3 ag(16, Bn);
  k_agg<1><<<ag, 256, 0, stream>>>(x0, ai1, E1, G1, aj1, F1, H1, den1, pm, x1, nullptr);
  k_scores2<<<8192, 256, 0, stream>>>(x1, asrc2, adst2, ai2, aj2, E2, G2, F2, H2);
  k_rowstats_pm<<<Bn * Nn, 256, 0, stream>>>(pm, ai2, aj2, den2);
  k_agg<2><<<ag, 256, 0, stream>>>(x1, ai2, E2, G2, aj2, F2, H2, den2, pm, nullptr, xmp);
  k_head<<<Bn, 256, 0, stream>>>(xmp, W1, b1, W2, b2, Wpi, bpi, Wv, bv, out);
}

// Round 5
// 546.304 us; speedup vs baseline: 2.1117x; 1.3063x over previous
//
#include <hip/hip_runtime.h>

#define Bn 64
#define Nn 1024
#define Cc 128

typedef _Float16 h8 __attribute__((ext_vector_type(8)));
typedef float f4v __attribute__((ext_vector_type(4)));
typedef unsigned long long u64;

// ---------------- featurize: x0 = nf @ W_in (fp16 grouped layout), ai/aj + exp tables ----------------
// grouped layout per batch: element (n,c) at ((n>>3)*128 + c)*8 + (n&7)
__global__ __launch_bounds__(256) void k_feat(
    const float* __restrict__ nf, const float* __restrict__ Win,
    const float* __restrict__ asrc, const float* __restrict__ adst,
    _Float16* __restrict__ X0, float* __restrict__ ai, float* __restrict__ aj,
    float* __restrict__ E, float* __restrict__ G, float* __restrict__ F, float* __restrict__ H) {
  int g = blockIdx.x; int b = g >> 7; int n0 = (g & 127) << 3;
  int t = threadIdx.x; int c = t >> 1; int h = t & 1;
  float w0 = Win[c], w1 = Win[Cc + c], w2 = Win[2 * Cc + c];
  float as_ = asrc[c], ad = adst[c];
  float ps[4], pd[4];
  _Float16 hv[4];
  #pragma unroll
  for (int r = 0; r < 4; r++) {
    int n = n0 + (h << 2) + r;
    const float* p = nf + ((size_t)(b << 10) + n) * 3;
    float x = p[0] * w0 + p[1] * w1 + p[2] * w2;
    hv[r] = (_Float16)x; ps[r] = x * as_; pd[r] = x * ad;
  }
  *(uint2*)(X0 + ((size_t)b << 17) + ((size_t)(g & 127) << 10) + (c << 3) + (h << 2)) = *(uint2*)hv;
  #pragma unroll
  for (int off = 32; off > 1; off >>= 1) {
    #pragma unroll
    for (int r = 0; r < 4; r++) { ps[r] += __shfl_down(ps[r], off, 64); pd[r] += __shfl_down(pd[r], off, 64); }
  }
  __shared__ float red[4][2][4][2];
  int lane = t & 63, wv = t >> 6;
  if (lane < 2) {
    #pragma unroll
    for (int r = 0; r < 4; r++) { red[wv][lane][r][0] = ps[r]; red[wv][lane][r][1] = pd[r]; }
  }
  __syncthreads();
  if (t < 8) {
    int hh = t >> 2, r = t & 3;
    float sa = 0.f, sd = 0.f;
    #pragma unroll
    for (int w = 0; w < 4; w++) { sa += red[w][hh][r][0]; sd += red[w][hh][r][1]; }
    int gi = (b << 10) + n0 + t;
    ai[gi] = sa; aj[gi] = sd;
    E[gi] = __expf(sa); G[gi] = __expf(0.2f * sa);
    F[gi] = __expf(sd); H[gi] = __expf(0.2f * sd);
  }
}

// ---------------- layer-2 scores from fp16 grouped x1 ----------------
__global__ __launch_bounds__(256) void k_scores2(
    const _Float16* __restrict__ X1,
    const float* __restrict__ asrc, const float* __restrict__ adst,
    float* __restrict__ ai, float* __restrict__ aj,
    float* __restrict__ E, float* __restrict__ G, float* __restrict__ F, float* __restrict__ H) {
  int g = blockIdx.x; int b = g >> 7; int n0 = (g & 127) << 3;
  int t = threadIdx.x; int c = t >> 1; int h = t & 1;
  float as_ = asrc[c], ad = adst[c];
  uint2 raw = *(const uint2*)(X1 + ((size_t)b << 17) + ((size_t)(g & 127) << 10) + (c << 3) + (h << 2));
  const _Float16* hp = (const _Float16*)&raw;
  float ps[4], pd[4];
  #pragma unroll
  for (int r = 0; r < 4; r++) { float x = (float)hp[r]; ps[r] = x * as_; pd[r] = x * ad; }
  #pragma unroll
  for (int off = 32; off > 1; off >>= 1) {
    #pragma unroll
    for (int r = 0; r < 4; r++) { ps[r] += __shfl_down(ps[r], off, 64); pd[r] += __shfl_down(pd[r], off, 64); }
  }
  __shared__ float red[4][2][4][2];
  int lane = t & 63, wv = t >> 6;
  if (lane < 2) {
    #pragma unroll
    for (int r = 0; r < 4; r++) { red[wv][lane][r][0] = ps[r]; red[wv][lane][r][1] = pd[r]; }
  }
  __syncthreads();
  if (t < 8) {
    int hh = t >> 2, r = t & 3;
    float sa = 0.f, sd = 0.f;
    #pragma unroll
    for (int w = 0; w < 4; w++) { sa += red[w][hh][r][0]; sd += red[w][hh][r][1]; }
    int gi = (b << 10) + n0 + t;
    ai[gi] = sa; aj[gi] = sd;
    E[gi] = __expf(sa); G[gi] = __expf(0.2f * sa);
    F[gi] = __expf(sd); H[gi] = __expf(0.2f * sd);
  }
}

// ------- MFMA aggregation with fused mask-pack (L1) and inline softmax denominator -------
// out[i,c] = relu( (1/den_i) * sum_j alpha_ij * x[j,c] ),  den_i = sum_j alpha_ij
// block: 64 i x 128 c, 4 waves (wave tile 32i x 64c), K-step 32 j, fp16 16x16x32 MFMA
template <int LAYER>
__global__ __launch_bounds__(256, 4) void k_agg(
    const _Float16* __restrict__ X, const int* __restrict__ adj,
    const float* __restrict__ ai, const float* __restrict__ E, const float* __restrict__ G,
    const float* __restrict__ aj, const float* __restrict__ F, const float* __restrict__ H,
    u64* __restrict__ pm, _Float16* __restrict__ Y, float* __restrict__ xmp) {
  __shared__ __align__(16) char smem[34304];
  _Float16* sB = (_Float16*)smem;                       // 8192 B: x tile (K-loop)
  _Float16* sA = (_Float16*)(smem + 8192);              // 4096 B: alpha tile [jg][i][8]
  float* s_aj = (float*)(smem + 12288);                 // 4 KB each
  float* s_F  = (float*)(smem + 16384);
  float* s_H  = (float*)(smem + 20480);
  unsigned char* s_pm = (unsigned char*)(smem + 24576); // 64 rows x 152 B (8B-aligned stride)
  float* tile = (float*)smem;                           // epilogue overlay [64][132]

  const int b = blockIdx.y, i0 = blockIdx.x << 6;
  const int tid = threadIdx.x;
  const int lane = tid & 63, wv = tid >> 6;
  const int m = lane & 15, quad = lane >> 4;
  const int wi = wv >> 1, wc = wv & 1;
  const int gbase = b << 10;

  // stage col-side arrays (aj, F, H) for all 1024 j
  ((float4*)s_aj)[tid] = ((const float4*)(aj + gbase))[tid];
  ((float4*)s_F)[tid]  = ((const float4*)(F + gbase))[tid];
  ((float4*)s_H)[tid]  = ((const float4*)(H + gbase))[tid];

  if (LAYER == 1) {
    // fused adjacency read + bit-pack: wave wv handles rows wv*16..wv*16+15.
    // lane L builds the 16-bit mask for j=16L..16L+15 in-register, then stores it
    // DIRECTLY to its final LDS slot (consumed only after the barrier below) and
    // to global pm viewed as ushort (consumed only by the LAYER-2 kernel).
    // No LDS read-back => no unsynchronized type-punned RAW hazard.
    ushort* pmu = (ushort*)pm;
    #pragma unroll 2
    for (int pass = 0; pass < 16; ++pass) {
      int r = (wv << 4) + pass;
      const uint4* arow = (const uint4*)(adj + ((size_t)(gbase + i0 + r) << 10));
      uint4 v0 = arow[(lane << 2) | 0], v1 = arow[(lane << 2) | 1];
      uint4 v2 = arow[(lane << 2) | 2], v3 = arow[(lane << 2) | 3];
      unsigned int bits =
          (v0.x) | (v0.y << 1) | (v0.z << 2) | (v0.w << 3) |
          (v1.x << 4) | (v1.y << 5) | (v1.z << 6) | (v1.w << 7) |
          (v2.x << 8) | (v2.y << 9) | (v2.z << 10) | (v2.w << 11) |
          (v3.x << 12) | (v3.y << 13) | (v3.z << 14) | (v3.w << 15);
      *(ushort*)(s_pm + r * 152 + (lane << 1)) = (ushort)bits;
      pmu[((size_t)(gbase + i0 + r) << 6) + lane] = (ushort)bits;
    }
  } else {
    // stage packed mask from global pm
    const u64* pmg = pm + (((size_t)(gbase + i0)) << 4);
    #pragma unroll
    for (int k = tid; k < 1024; k += 256) {
      int r = k >> 4, w = k & 15;
      *(u64*)(s_pm + r * 152 + (w << 3)) = pmg[k];
    }
  }

  // per-thread A-gen row constants (thread owns row i = lane, j-group = wv)
  const int gi = gbase + i0 + lane;
  const float ai_i = ai[gi];
  const float Ed = E[gi], Gd = G[gi];   // raw (unnormalized) — den folded into epilogue
  float dsum = 0.f;

  f4v acc[2][4];
  #pragma unroll
  for (int a = 0; a < 2; a++)
    #pragma unroll
    for (int ct = 0; ct < 4; ct++) { f4v z = {0.f, 0.f, 0.f, 0.f}; acc[a][ct] = z; }

  const char* xb = (const char*)(X + ((size_t)b << 17));
  __syncthreads();  // staging (s_aj/s_F/s_H/s_pm) visible to all waves

  for (int kt = 0; kt < 32; ++kt) {
    const int jt = kt << 5;
    // B-tile slice -> VGPRs (grouped layout is contiguous per tile)
    const char* gsrc = xb + (jt << 8) + (wv << 11) + lane * 16;
    uint4 r0 = *(const uint4*)gsrc;
    uint4 r1 = *(const uint4*)(gsrc + 1024);
    // A-gen: alpha for (i = lane, j = jt + wv*8 + jj)
    h8 af;
    {
      const int j0 = jt + (wv << 3);
      float aw[8], fw[8], hw[8];
      *(float4*)&aw[0] = *(const float4*)&s_aj[j0]; *(float4*)&aw[4] = *(const float4*)&s_aj[j0 + 4];
      *(float4*)&fw[0] = *(const float4*)&s_F[j0];  *(float4*)&fw[4] = *(const float4*)&s_F[j0 + 4];
      *(float4*)&hw[0] = *(const float4*)&s_H[j0];  *(float4*)&hw[4] = *(const float4*)&s_H[j0 + 4];
      unsigned int mbyte = s_pm[lane * 152 + (jt >> 3) + wv];
      #pragma unroll
      for (int jj = 0; jj < 8; jj++) {
        float e = ai_i + aw[jj];
        bool pos = e > 0.f;
        float wi_ = pos ? Ed : Gd;
        float wj_ = pos ? fw[jj] : hw[jj];
        float val = ((mbyte >> jj) & 1u) ? wi_ * wj_ : 0.f;
        dsum += val;
        af[jj] = (_Float16)val;
      }
    }
    __syncthreads();  // prev-iter MFMA ds_reads of sA/sB complete
    {
      char* ldst = (char*)sB + (wv << 11) + lane * 16;
      *(uint4*)ldst = r0;
      *(uint4*)(ldst + 1024) = r1;
      *((h8*)sA + (wv << 6) + lane) = af;
    }
    __syncthreads();  // sB + sA visible
    // MFMA
    {
      const h8* pA = (const h8*)sA;
      const h8* pB = (const h8*)sB;
      h8 a0 = pA[(quad << 6) + (wi << 5) + m];
      h8 a1 = pA[(quad << 6) + (wi << 5) + 16 + m];
      #pragma unroll
      for (int ct = 0; ct < 4; ct++) {
        h8 bf = pB[(quad << 7) + (wc << 6) + (ct << 4) + m];
        acc[0][ct] = __builtin_amdgcn_mfma_f32_16x16x32_f16(a0, bf, acc[0][ct], 0, 0, 0);
        acc[1][ct] = __builtin_amdgcn_mfma_f32_16x16x32_f16(a1, bf, acc[1][ct], 0, 0, 0);
      }
    }
  }
  __syncthreads();  // K-loop LDS reads done
  // denominator reduction: dsum_s[i][wv], each row's den = sum of 4 wave partials
  float* dsum_s = (float*)(smem + 12288);  // overlays s_aj (no longer needed)
  dsum_s[(lane << 2) + wv] = dsum;
  __syncthreads();
  float rd8[2][4];
  #pragma unroll
  for (int a = 0; a < 2; a++)
    #pragma unroll
    for (int r = 0; r < 4; r++) {
      int lr = (wi << 5) + (a << 4) + (quad << 2) + r;
      float4 d4 = *(const float4*)&dsum_s[lr << 2];
      rd8[a][r] = 1.0f / ((d4.x + d4.y) + (d4.z + d4.w));
    }
  __syncthreads();  // dsum reads done before tile overlay overwrites the region
  // write relu(acc/den) into fp32 tile [64][132]
  #pragma unroll
  for (int a = 0; a < 2; a++)
    #pragma unroll
    for (int ct = 0; ct < 4; ct++)
      #pragma unroll
      for (int r = 0; r < 4; r++) {
        int lr = (wi << 5) + (a << 4) + (quad << 2) + r;
        int c = (wc << 6) + (ct << 4) + m;
        tile[lr * 132 + c] = fmaxf(acc[a][ct][r] * rd8[a][r], 0.f);
      }
  __syncthreads();
  if (LAYER == 1) {
    // coalesced fp16 grouped-layout store: block region is contiguous [i0*128, +8192)
    _Float16 hv[32];
    #pragma unroll
    for (int s = 0; s < 32; s++) {
      int q = (tid << 5) + s;
      int li = ((q >> 10) << 3) + (q & 7), c = (q >> 3) & 127;
      hv[s] = (_Float16)tile[li * 132 + c];
    }
    uint4* o = (uint4*)(Y + ((size_t)b << 17) + ((size_t)i0 << 7) + (tid << 5));
    o[0] = *(uint4*)&hv[0]; o[1] = *(uint4*)&hv[8];
    o[2] = *(uint4*)&hv[16]; o[3] = *(uint4*)&hv[24];
  } else {
    // node-mean partial: column sums -> per-(block,batch) partial slot (deterministic)
    if (tid < 128) {
      float s = 0.f;
      #pragma unroll
      for (int i = 0; i < 64; i++) s += tile[i * 132 + tid];
      xmp[(((b << 4) + blockIdx.x) << 7) + tid] = s;
    }
  }
}

// ---------------- fused MLP head (sums the 16 mean-partials) ----------------
__global__ __launch_bounds__(256) void k_head(
    const float* __restrict__ xmp, const float* __restrict__ W1, const float* __restrict__ b1,
    const float* __restrict__ W2, const float* __restrict__ b2,
    const float* __restrict__ Wpi, const float* __restrict__ bpi,
    const float* __restrict__ Wv, const float* __restrict__ bv,
    float* __restrict__ out) {
  int b = blockIdx.x, t = threadIdx.x;
  __shared__ float xs[128], h1[256], h2[128], red[4];
  if (t < 128) {
    const float* p = xmp + ((size_t)b << 11);
    float s = 0.f;
    #pragma unroll
    for (int xb = 0; xb < 16; xb++) s += p[(xb << 7) + t];
    xs[t] = s * (1.f / 1024.f);
  }
  __syncthreads();
  float s = 0.f;
  #pragma unroll 8
  for (int k = 0; k < 128; k++) s += xs[k] * W1[k * 256 + t];
  h1[t] = fmaxf(s + b1[t], 0.f);
  __syncthreads();
  if (t < 128) {
    float s2 = 0.f;
    #pragma unroll 8
    for (int k = 0; k < 256; k++) s2 += h1[k] * W2[k * 128 + t];
    h2[t] = fmaxf(s2 + b2[t], 0.f);
  }
  __syncthreads();
  float lg[4];
  #pragma unroll
  for (int q = 0; q < 4; q++) {
    int o = t + (q << 8);
    float s3 = 0.f;
    #pragma unroll 8
    for (int k = 0; k < 128; k++) s3 += h2[k] * Wpi[k * 1024 + o];
    lg[q] = s3 + bpi[o];
  }
  float mx = fmaxf(fmaxf(lg[0], lg[1]), fmaxf(lg[2], lg[3]));
  #pragma unroll
  for (int off = 32; off > 0; off >>= 1) mx = fmaxf(mx, __shfl_down(mx, off, 64));
  if ((t & 63) == 0) red[t >> 6] = mx;
  __syncthreads();
  mx = fmaxf(fmaxf(red[0], red[1]), fmaxf(red[2], red[3]));
  __syncthreads();
  float ex[4]; float sum = 0.f;
  #pragma unroll
  for (int q = 0; q < 4; q++) { ex[q] = __expf(lg[q] - mx); sum += ex[q]; }
  #pragma unroll
  for (int off = 32; off > 0; off >>= 1) sum += __shfl_down(sum, off, 64);
  if ((t & 63) == 0) red[t >> 6] = sum;
  __syncthreads();
  sum = red[0] + red[1] + red[2] + red[3];
  float rs = 1.0f / sum;
  #pragma unroll
  for (int q = 0; q < 4; q++) out[((size_t)b << 10) + t + (q << 8)] = ex[q] * rs;
  __syncthreads();
  float vp = (t < 128) ? h2[t] * Wv[t] : 0.f;
  #pragma unroll
  for (int off = 32; off > 0; off >>= 1) vp += __shfl_down(vp, off, 64);
  if ((t & 63) == 0) red[t >> 6] = vp;
  __syncthreads();
  if (t == 0) out[65536 + b] = red[0] + red[1] + red[2] + red[3] + bv[0];
}

extern "C" void kernel_launch(void* const* d_in, const int* in_sizes, int n_in,
                              void* d_out, int out_size, void* d_ws, size_t ws_size,
                              hipStream_t stream) {
  const float* nf    = (const float*)d_in[0];
  const int*   adj   = (const int*)  d_in[1];
  const float* Win   = (const float*)d_in[2];
  const float* asrc  = (const float*)d_in[3];
  const float* adst  = (const float*)d_in[4];
  const float* asrc2 = (const float*)d_in[5];
  const float* adst2 = (const float*)d_in[6];
  const float* W1    = (const float*)d_in[7];
  const float* b1    = (const float*)d_in[8];
  const float* W2    = (const float*)d_in[9];
  const float* b2    = (const float*)d_in[10];
  const float* Wpi   = (const float*)d_in[11];
  const float* bpi   = (const float*)d_in[12];
  const float* Wv    = (const float*)d_in[13];
  const float* bv    = (const float*)d_in[14];
  float* out = (float*)d_out;

  char* ws = (char*)d_ws;
  _Float16* x0 = (_Float16*)(ws);                                // 16.78 MB
  _Float16* x1 = (_Float16*)(ws + 16777216);                     // 16.78 MB
  u64* pm = (u64*)(ws + 33554432);                               // 8.39 MB
  char* S = ws + 41943040;
  float* ai1 = (float*)(S + 0 * 262144);
  float* aj1 = (float*)(S + 1 * 262144);
  float* E1  = (float*)(S + 2 * 262144);
  float* G1  = (float*)(S + 3 * 262144);
  float* F1  = (float*)(S + 4 * 262144);
  float* H1  = (float*)(S + 5 * 262144);
  float* ai2 = (float*)(S + 6 * 262144);
  float* aj2 = (float*)(S + 7 * 262144);
  float* E2  = (float*)(S + 8 * 262144);
  float* G2  = (float*)(S + 9 * 262144);
  float* F2  = (float*)(S + 10 * 262144);
  float* H2  = (float*)(S + 11 * 262144);
  float* xmp = (float*)(S + 12 * 262144);                        // 512 KB partials

  k_feat<<<8192, 256, 0, stream>>>(nf, Win, asrc, adst, x0, ai1, aj1, E1, G1, F1, H1);
  dim3 ag(16, Bn);
  k_agg<1><<<ag, 256, 0, stream>>>(x0, adj, ai1, E1, G1, aj1, F1, H1, pm, x1, nullptr);
  k_scores2<<<8192, 256, 0, stream>>>(x1, asrc2, adst2, ai2, aj2, E2, G2, F2, H2);
  k_agg<2><<<ag, 256, 0, stream>>>(x1, nullptr, ai2, E2, G2, aj2, F2, H2, pm, nullptr, xmp);
  k_head<<<Bn, 256, 0, stream>>>(xmp, W1, b1, W2, b2, Wpi, bpi, Wv, bv, out);
}